// Round 5
// baseline (22644.275 us; speedup 1.0000x reference)
//
#include <hip/hip_runtime.h>

// ---------------------------------------------------------------------------
// 2-layer LSTM, T=1024, B=32, D=256, H=512. Inputs fp32, OUTPUT fp32.
//   pack_w: fp32 W_hh -> bf16 MFMA A-fragment order (register-resident).
//   gemm_xp: xp = A @ W^T (bf16 MFMA), plain [t*32+b][2048] bf16 layout.
//   lstm_rec: persistent 8-wg kernel. Wave owns 16 h-cols x 4 gates; weights
//     in 256 VGPRs/lane. MFMA A=W, B=h so C rows = h-cols: each lane holds all
//     4 gates for 4 contiguous j's -> no LDS exchange. Cross-wg h exchange via
//     relaxed agent atomics (write-through, cache-bypass) + explicit
//     s_waitcnt: NO buffer_wbl2 / buffer_inv per step (R4's 7us/step killer).
// ---------------------------------------------------------------------------

typedef __bf16 bf16x4 __attribute__((ext_vector_type(4)));
typedef __bf16 bf16x8 __attribute__((ext_vector_type(8)));
typedef float  f32x4  __attribute__((ext_vector_type(4)));
typedef unsigned long long u64;

#define MFMA16(a, b, c) __builtin_amdgcn_mfma_f32_16x16x32_bf16((a), (b), (c), 0, 0, 0)
#define SCOPE_AGENT __HIP_MEMORY_SCOPE_AGENT

__device__ __forceinline__ float fsigm(float x) { return 1.0f / (1.0f + __expf(-x)); }
__device__ __forceinline__ float ftanh(float x) {
    x = fminf(15.0f, fmaxf(-15.0f, x));
    float e = __expf(2.0f * x);
    return (e - 1.0f) / (e + 1.0f);
}

__device__ __forceinline__ bf16x8 frag_from(u64 lo, u64 hi) {
    union { u64 u[2]; bf16x8 v; } x;
    x.u[0] = lo; x.u[1] = hi;
    return x.v;
}

// ---------------------------------------------------------------------------
// Pack W_hh [2048][512] fp32 -> bf16 A-fragment order per (w0..7, v0..3, g0..3,
// kk0..15): WB[tid*8+e] = W[g*512 + w*64 + v*16 + (lane&15)][kk*32+(lane>>4)*8+e]
// ---------------------------------------------------------------------------
__global__ void pack_w(const float* __restrict__ W0, const float* __restrict__ W1,
                       __bf16* __restrict__ WB0, __bf16* __restrict__ WB1) {
    int gtid = blockIdx.x * 256 + threadIdx.x;         // 0 .. 262143
    const float* W = (gtid < 131072) ? W0 : W1;
    __bf16* WB     = (gtid < 131072) ? WB0 : WB1;
    int tid  = gtid & 131071;
    int lane = tid & 63;
    int kk   = (tid >> 6) & 15;
    int g    = (tid >> 10) & 3;
    int v    = (tid >> 12) & 3;
    int w    = tid >> 14;                               // 0..7
    int grow = g * 512 + w * 64 + v * 16 + (lane & 15);
    int k0   = kk * 32 + (lane >> 4) * 8;
    const float* src = W + (size_t)grow * 512 + k0;
    bf16x8 val;
#pragma unroll
    for (int e = 0; e < 8; e++) val[e] = (__bf16)src[e];
    *(bf16x8*)(WB + (size_t)tid * 8) = val;
}

// ---------------------------------------------------------------------------
// xp[r][n] = sum_k Arow(r)[k] * W[n][k],  r = t*32+b (t-major), n in [0,2048)
// a_fp32_perm=1: A fp32, Arow(r) = A + ((r&31)*1024 + (r>>5))*K  (x is [B,T,D])
// a_fp32_perm=0: A bf16 row-major [32768][K]
// ---------------------------------------------------------------------------
__global__ __launch_bounds__(256, 2) void gemm_xp(const void* __restrict__ Av,
                                                  const float* __restrict__ W,
                                                  __bf16* __restrict__ out,
                                                  int K, int a_fp32_perm) {
    const int tid = threadIdx.x, lane = tid & 63, wv = tid >> 6;
    const int bm = blockIdx.x >> 4, bn = blockIdx.x & 15;
    const int m_base = bm * 128 + (wv & 1) * 64;
    const int n_base = bn * 128 + (wv >> 1) * 64;
    const int kq = (lane >> 4) * 8;
    const int rl = lane & 15;

    f32x4 acc[4][4];
#pragma unroll
    for (int i = 0; i < 4; i++)
#pragma unroll
        for (int j = 0; j < 4; j++) acc[i][j] = (f32x4){0.f, 0.f, 0.f, 0.f};

    const int nk = K >> 5;
    for (int kk = 0; kk < nk; kk++) {
        int k0 = kk * 32 + kq;
        bf16x8 af[4], bfr[4];
#pragma unroll
        for (int mt = 0; mt < 4; mt++) {
            int row = m_base + mt * 16 + rl;
            if (a_fp32_perm) {
                const float* A = (const float*)Av;
                const float* ap = A + (size_t)((row & 31) * 1024 + (row >> 5)) * K + k0;
#pragma unroll
                for (int e = 0; e < 8; e++) af[mt][e] = (__bf16)ap[e];
            } else {
                const __bf16* A = (const __bf16*)Av;
                af[mt] = *(const bf16x8*)(A + (size_t)row * K + k0);
            }
        }
#pragma unroll
        for (int nt = 0; nt < 4; nt++) {
            int n = n_base + nt * 16 + rl;
            const float* wp = W + (size_t)n * K + k0;
#pragma unroll
            for (int e = 0; e < 8; e++) bfr[nt][e] = (__bf16)wp[e];
        }
#pragma unroll
        for (int mt = 0; mt < 4; mt++)
#pragma unroll
            for (int nt = 0; nt < 4; nt++)
                acc[mt][nt] = MFMA16(af[mt], bfr[nt], acc[mt][nt]);
    }

    const int rq = (lane >> 4) * 4;
#pragma unroll
    for (int mt = 0; mt < 4; mt++)
#pragma unroll
        for (int nt = 0; nt < 4; nt++)
#pragma unroll
            for (int r = 0; r < 4; r++) {
                int row = m_base + mt * 16 + rq + r;
                int col = n_base + nt * 16 + rl;
                out[(size_t)row * 2048 + col] = (__bf16)acc[mt][nt][r];
            }
}

// ---------------------------------------------------------------------------
// Persistent recurrence, 8 wgs x 256. Wave v of wg w owns j-cols
// [w*64+v*16, +16) for all 4 gates. MFMA: A=Wslice (m=j), B=h (n=batch).
// C-frag: col=lane&15 -> batch, row=(lane>>4)*4+r -> j. Lane owns all 4 gates
// of (b=col(+16), j=jbase+r) -> gate math fully in-register.
// ---------------------------------------------------------------------------
__global__ __launch_bounds__(256, 1) void lstm_rec(
    const __bf16* __restrict__ xp,    // [32768][2048] bf16, row = t*32+b
    const __bf16* __restrict__ WB,    // packed weights, 2 MB
    const float* __restrict__ bias,   // [2048] fp32
    __bf16* __restrict__ hbuf,        // [2][32][512] double buffer (zeroed)
    __bf16* __restrict__ hs0_bf,      // layer0 only: hs0[t*32+b][512] bf16
    float* __restrict__ out_f32,      // layer1 only: out[b][t][512] fp32
    float* __restrict__ hn_out,       // [32][512] fp32
    float* __restrict__ cn_out,       // [32][512] fp32
    int* flags,                       // [1024][8] zeroed
    int layer) {
    const int tid  = threadIdx.x;
    const int w    = blockIdx.x;   // 0..7
    const int lane = tid & 63;
    const int v    = tid >> 6;     // wave 0..3

    // --- weights resident in registers: wreg[g][kk], 256 VGPRs/lane ---
    bf16x8 wreg[4][16];
    {
        const __bf16* wb = WB + ((size_t)(w * 4 + v) * 4 * 16) * 512 + lane * 8;
#pragma unroll
        for (int g = 0; g < 4; g++)
#pragma unroll
            for (int kk = 0; kk < 16; kk++)
                wreg[g][kk] = *(const bf16x8*)(wb + (size_t)(g * 16 + kk) * 512);
    }

    // --- elementwise mapping: lane -> batch col + 4 contiguous j's ---
    const int bcol  = lane & 15;            // batch within half
    const int q     = lane >> 4;
    const int jbase = w * 64 + v * 16 + q * 4;
    f32x4 bsv[4];
#pragma unroll
    for (int g = 0; g < 4; g++) bsv[g] = *(const f32x4*)(bias + g * 512 + jbase);
    f32x4 cc[2] = {(f32x4){0.f, 0.f, 0.f, 0.f}, (f32x4){0.f, 0.f, 0.f, 0.f}};

    const int boff = (lane & 15) * 512 + (lane >> 4) * 8;  // h B-frag lane offset

    // xp prefetch: u64 per (gate, half) = 4 contiguous bf16
    u64 xc[4][2], xn[4][2];
#pragma unroll
    for (int g = 0; g < 4; g++)
#pragma unroll
        for (int p = 0; p < 2; p++)
            xc[g][p] = *(const u64*)(xp + (size_t)(bcol + p * 16) * 2048 + g * 512 + jbase);

    for (int t = 0; t < 1024; t++) {
        // prefetch xp[t+1] (independent of h)
        {
            int tn = (t < 1023) ? t + 1 : 1023;
#pragma unroll
            for (int g = 0; g < 4; g++)
#pragma unroll
                for (int p = 0; p < 2; p++)
                    xn[g][p] = *(const u64*)(xp + (size_t)(tn * 32 + bcol + p * 16) * 2048 +
                                             g * 512 + jbase);
        }

        // --- MFMA: gates[j][b] = Wslice @ h^T; h read via agent atomics ---
        const __bf16* hc = hbuf + (size_t)(t & 1) * 16384;
        f32x4 acc[4][2];
#pragma unroll
        for (int g = 0; g < 4; g++)
#pragma unroll
            for (int p = 0; p < 2; p++) acc[g][p] = (f32x4){0.f, 0.f, 0.f, 0.f};
#pragma unroll
        for (int kk = 0; kk < 16; kk++) {
            const __bf16* hp = hc + boff + kk * 32;
            u64 a0l = __hip_atomic_load((const u64*)hp,            __ATOMIC_RELAXED, SCOPE_AGENT);
            u64 a0h = __hip_atomic_load((const u64*)(hp + 4),      __ATOMIC_RELAXED, SCOPE_AGENT);
            u64 a1l = __hip_atomic_load((const u64*)(hp + 8192),   __ATOMIC_RELAXED, SCOPE_AGENT);
            u64 a1h = __hip_atomic_load((const u64*)(hp + 8196),   __ATOMIC_RELAXED, SCOPE_AGENT);
            bf16x8 hb0 = frag_from(a0l, a0h);
            bf16x8 hb1 = frag_from(a1l, a1h);
#pragma unroll
            for (int g = 0; g < 4; g++) {
                acc[g][0] = MFMA16(wreg[g][kk], hb0, acc[g][0]);
                acc[g][1] = MFMA16(wreg[g][kk], hb1, acc[g][1]);
            }
        }

        // --- gate math, fully in-register ---
        __bf16* hnx = hbuf + (size_t)((t + 1) & 1) * 16384;
#pragma unroll
        for (int p = 0; p < 2; p++) {
            int b = bcol + p * 16;
            union { u64 u; bf16x4 v; } xi, xf, xg, xo;
            xi.u = xc[0][p]; xf.u = xc[1][p]; xg.u = xc[2][p]; xo.u = xc[3][p];
            bf16x4 hb;
            f32x4 hf;
#pragma unroll
            for (int r = 0; r < 4; r++) {
                float ig = acc[0][p][r] + (float)xi.v[r] + bsv[0][r];
                float fg = acc[1][p][r] + (float)xf.v[r] + bsv[1][r];
                float gg = acc[2][p][r] + (float)xg.v[r] + bsv[2][r];
                float og = acc[3][p][r] + (float)xo.v[r] + bsv[3][r];
                float iv = fsigm(ig), fv = fsigm(fg), gv = ftanh(gg), ov = fsigm(og);
                cc[p][r] = fv * cc[p][r] + iv * gv;
                float hv = ov * ftanh(cc[p][r]);
                hf[r] = hv;
                hb[r] = (__bf16)hv;
            }
            union { bf16x4 v; u64 u; } hu; hu.v = hb;
            __hip_atomic_store((u64*)(hnx + (size_t)b * 512 + jbase), hu.u,
                               __ATOMIC_RELAXED, SCOPE_AGENT);
            if (layer == 0)
                *(bf16x4*)(hs0_bf + ((size_t)t * 32 + b) * 512 + jbase) = hb;
            else
                *(f32x4*)(out_f32 + (size_t)b * 524288 + (size_t)t * 512 + jbase) = hf;
            if (t == 1023) {
                *(f32x4*)(hn_out + (size_t)b * 512 + jbase) = hf;
                *(f32x4*)(cn_out + (size_t)b * 512 + jbase) = cc[p];
            }
        }

        // --- 8-wg flag barrier: no cache maintenance ops ---
        if (t < 1023) {
            asm volatile("s_waitcnt vmcnt(0)" ::: "memory");  // h stores at coherence point
            __syncthreads();                                   // whole wg drained
            if (tid == 0)
                __hip_atomic_store(&flags[t * 8 + w], 1, __ATOMIC_RELAXED, SCOPE_AGENT);
            if (tid < 8) {
                while (__hip_atomic_load(&flags[t * 8 + tid], __ATOMIC_RELAXED,
                                         SCOPE_AGENT) == 0) {}
            }
            asm volatile("" ::: "memory");
            __syncthreads();
        }
#pragma unroll
        for (int g = 0; g < 4; g++)
#pragma unroll
            for (int p = 0; p < 2; p++) xc[g][p] = xn[g][p];
    }
}

// ---------------------------------------------------------------------------
extern "C" void kernel_launch(void* const* d_in, const int* in_sizes, int n_in,
                              void* d_out, int out_size, void* d_ws, size_t ws_size,
                              hipStream_t stream) {
    (void)in_sizes; (void)n_in; (void)out_size; (void)ws_size;
    const float* x    = (const float*)d_in[0];  // [32][1024][256] fp32
    const float* Wih0 = (const float*)d_in[1];  // [2048][256] fp32
    const float* b0   = (const float*)d_in[2];  // [2048] fp32
    const float* Whh0 = (const float*)d_in[3];  // [2048][512] fp32
    const float* Wih1 = (const float*)d_in[4];  // [2048][512] fp32
    const float* b1   = (const float*)d_in[5];  // [2048] fp32
    const float* Whh1 = (const float*)d_in[6];  // [2048][512] fp32
    float* dout = (float*)d_out;  // fp32: out(16777216) | h_n(2*16384) | c_n(2*16384)

    char* wsb = (char*)d_ws;
    int*    flags = (int*)wsb;                                   // 64 KB used (2 layers)
    __bf16* hbuf0 = (__bf16*)(wsb + (256 << 10));                // 64 KB
    __bf16* hbuf1 = (__bf16*)(wsb + (320 << 10));                // 64 KB
    __bf16* WB0   = (__bf16*)(wsb + (384 << 10));                // 2 MB
    __bf16* WB1   = (__bf16*)(wsb + (384 << 10) + (2 << 20));    // 2 MB
    __bf16* hs0   = (__bf16*)(wsb + (384 << 10) + (4 << 20));    // 32 MB
    __bf16* xpb   = (__bf16*)(wsb + (384 << 10) + (36 << 20));   // 128 MB (xp0/xp1 shared)

    // zero flags + both h double-buffers
    (void)hipMemsetAsync(wsb, 0, 384 << 10, stream);

    pack_w<<<dim3(1024), dim3(256), 0, stream>>>(Whh0, Whh1, WB0, WB1);

    // layer 0: xp0 = x @ Wih0^T  (K=256, fp32 A, permuted rows)
    gemm_xp<<<dim3(4096), dim3(256), 0, stream>>>((const void*)x, Wih0, xpb, 256, 1);
    lstm_rec<<<dim3(8), dim3(256), 0, stream>>>(
        xpb, WB0, b0, hbuf0, hs0, (float*)nullptr,
        dout + 16777216, dout + 16777216 + 32768, flags, 0);

    // layer 1: xp1 = hs0 @ Wih1^T  (K=512, bf16 A row-major)
    gemm_xp<<<dim3(4096), dim3(256), 0, stream>>>((const void*)hs0, Wih1, xpb, 512, 0);
    lstm_rec<<<dim3(8), dim3(256), 0, stream>>>(
        xpb, WB1, b1, hbuf1, (__bf16*)nullptr, dout,
        dout + 16777216 + 16384, dout + 16777216 + 32768 + 16384, flags + 8192, 1);
}

// Round 6
// 7783.443 us; speedup vs baseline: 2.9093x; 2.9093x over previous
//
#include <hip/hip_runtime.h>

// ---------------------------------------------------------------------------
// 2-layer LSTM, T=1024, B=32, D=256, H=512. Inputs fp32, OUTPUT fp32.
//   pack_w: fp32 W_hh -> bf16 MFMA B-fragment order (register-resident).
//   gemm_xp: xp = A @ W^T (bf16 MFMA), [t*32+b][2048] bf16 layout.
//   lstm_rec: persistent 32-wg kernel (R4 structure, 72 VGPR, LDS gate
//     exchange) + R5's fence-free relaxed agent-atomic h exchange, with the
//     atomic h loads BATCHED UPFRONT (R5's mistake: atomics interleaved with
//     MFMAs serialize at ~900cyc each). h staged to LDS (stride 516 -> ~2-way
//     conflicts, free), then b64 fragment reads.
// ---------------------------------------------------------------------------

typedef __bf16 bf16x8 __attribute__((ext_vector_type(8)));
typedef float  f32x4  __attribute__((ext_vector_type(4)));
typedef float  f32x2  __attribute__((ext_vector_type(2)));
typedef unsigned long long u64;
typedef unsigned int u32;

#define MFMA16(a, b, c) __builtin_amdgcn_mfma_f32_16x16x32_bf16((a), (b), (c), 0, 0, 0)
#define SCOPE_AGENT __HIP_MEMORY_SCOPE_AGENT

__device__ __forceinline__ float fsigm(float x) { return 1.0f / (1.0f + __expf(-x)); }
__device__ __forceinline__ float ftanh(float x) {
    x = fminf(15.0f, fmaxf(-15.0f, x));
    float e = __expf(2.0f * x);
    return (e - 1.0f) / (e + 1.0f);
}

__device__ __forceinline__ bf16x8 frag_from(u64 lo, u64 hi) {
    union { u64 u[2]; bf16x8 v; } x;
    x.u[0] = lo; x.u[1] = hi;
    return x.v;
}

// ---------------------------------------------------------------------------
// Pack W_hh [2048][512] fp32 into per-(wg,wave,ktile) bf16 B-fragment order
// (R4 layout): WB[((w*4+v)*16+kk)*512 + lane*8 + e] = bf16(W[grow][k0+e])
//   n = v*16 + (lane&15)  (wg-local col, packing [i(16) f(16) g(16) o(16)])
//   grow = (n>>4)*512 + w*16 + (n&15) ; k0 = kk*32 + (lane>>4)*8
// ---------------------------------------------------------------------------
__global__ void pack_w(const float* __restrict__ W0, const float* __restrict__ W1,
                       __bf16* __restrict__ WB0, __bf16* __restrict__ WB1) {
    int gtid = blockIdx.x * 256 + threadIdx.x;         // 0 .. 262143
    const float* W = (gtid < 131072) ? W0 : W1;
    __bf16* WB     = (gtid < 131072) ? WB0 : WB1;
    int tid  = gtid & 131071;
    int lane = tid & 63;
    int kk   = (tid >> 6) & 15;
    int v    = (tid >> 10) & 3;
    int w    = tid >> 12;                               // 0..31
    int n    = v * 16 + (lane & 15);
    int grow = (n >> 4) * 512 + w * 16 + (n & 15);
    int k0   = kk * 32 + (lane >> 4) * 8;
    const float* src = W + (size_t)grow * 512 + k0;
    bf16x8 val;
#pragma unroll
    for (int e = 0; e < 8; e++) val[e] = (__bf16)src[e];
    *(bf16x8*)(WB + (size_t)tid * 8) = val;
}

// ---------------------------------------------------------------------------
// xp[r][n] = sum_k Arow(r)[k] * W[n][k],  r = t*32+b (t-major), n in [0,2048)
// a_fp32_perm=1: A fp32, Arow(r) = A + ((r&31)*1024 + (r>>5))*K  (x is [B,T,D])
// a_fp32_perm=0: A bf16 row-major [32768][K]
// ---------------------------------------------------------------------------
__global__ __launch_bounds__(256, 2) void gemm_xp(const void* __restrict__ Av,
                                                  const float* __restrict__ W,
                                                  __bf16* __restrict__ out,
                                                  int K, int a_fp32_perm) {
    const int tid = threadIdx.x, lane = tid & 63, wv = tid >> 6;
    const int bm = blockIdx.x >> 4, bn = blockIdx.x & 15;
    const int m_base = bm * 128 + (wv & 1) * 64;
    const int n_base = bn * 128 + (wv >> 1) * 64;
    const int kq = (lane >> 4) * 8;
    const int rl = lane & 15;

    f32x4 acc[4][4];
#pragma unroll
    for (int i = 0; i < 4; i++)
#pragma unroll
        for (int j = 0; j < 4; j++) acc[i][j] = (f32x4){0.f, 0.f, 0.f, 0.f};

    const int nk = K >> 5;
    for (int kk = 0; kk < nk; kk++) {
        int k0 = kk * 32 + kq;
        bf16x8 af[4], bfr[4];
#pragma unroll
        for (int mt = 0; mt < 4; mt++) {
            int row = m_base + mt * 16 + rl;
            if (a_fp32_perm) {
                const float* A = (const float*)Av;
                const float* ap = A + (size_t)((row & 31) * 1024 + (row >> 5)) * K + k0;
#pragma unroll
                for (int e = 0; e < 8; e++) af[mt][e] = (__bf16)ap[e];
            } else {
                const __bf16* A = (const __bf16*)Av;
                af[mt] = *(const bf16x8*)(A + (size_t)row * K + k0);
            }
        }
#pragma unroll
        for (int nt = 0; nt < 4; nt++) {
            int n = n_base + nt * 16 + rl;
            const float* wp = W + (size_t)n * K + k0;
#pragma unroll
            for (int e = 0; e < 8; e++) bfr[nt][e] = (__bf16)wp[e];
        }
#pragma unroll
        for (int mt = 0; mt < 4; mt++)
#pragma unroll
            for (int nt = 0; nt < 4; nt++)
                acc[mt][nt] = MFMA16(af[mt], bfr[nt], acc[mt][nt]);
    }

    const int rq = (lane >> 4) * 4;
#pragma unroll
    for (int mt = 0; mt < 4; mt++)
#pragma unroll
        for (int nt = 0; nt < 4; nt++)
#pragma unroll
            for (int r = 0; r < 4; r++) {
                int row = m_base + mt * 16 + rq + r;
                int col = n_base + nt * 16 + rl;
                out[(size_t)row * 2048 + col] = (__bf16)acc[mt][nt][r];
            }
}

// ---------------------------------------------------------------------------
// Persistent recurrence, 32 wgs x 256. wg w owns j in [w*16,(w+1)*16) for all
// 4 gates (64 gate cols); wave v computes gate-col slice v*16..+16. Per step:
//  1) batched atomic u64 loads of full h (32 KB) -> LDS mirror (stride 516)
//  2) b64 frag reads + 32 MFMAs/wave (A=h, B=wreg)
//  3) gates via g_lds -> in-register c update (thread owns (b, j0, j1))
//  4) one u32 atomic h store/thread -> waitcnt -> flag -> overlap hs0/out
//     stores with flag propagation -> poll 32 flags -> syncthreads
// No buffer_wbl2/buffer_inv anywhere (fence-free protocol proven in R5).
// ---------------------------------------------------------------------------
__global__ __launch_bounds__(256, 1) void lstm_rec(
    const __bf16* __restrict__ xp,    // [32768][2048] bf16, row = t*32+b
    const __bf16* __restrict__ WB,    // packed weights, 2 MB
    const float* __restrict__ bias,   // [2048] fp32
    __bf16* __restrict__ hbuf,        // [2][32][512] double buffer (zeroed)
    __bf16* __restrict__ hs0_bf,      // layer0 only: hs0[t*32+b][512] bf16
    float* __restrict__ out_f32,      // layer1 only: out[b][t][512] fp32
    float* __restrict__ hn_out,       // [32][512] fp32
    float* __restrict__ cn_out,       // [32][512] fp32
    int* flags,                       // [1024][32] zeroed
    int layer) {
    const int tid  = threadIdx.x;
    const int w    = blockIdx.x;   // 0..31
    const int lane = tid & 63;
    const int wv   = tid >> 6;     // wave 0..3

    __shared__ __bf16 h_lds[32 * 516];  // h mirror, stride 516 (~2-way conflicts)
    __shared__ float  g_lds[32 * 68];   // gates [32 b][64 cols], +4 pad

    // --- weights resident in registers (64 VGPRs/lane) ---
    bf16x8 wreg[16];
    {
        const __bf16* wb = WB + (size_t)(w * 4 + wv) * 16 * 512 + lane * 8;
#pragma unroll
        for (int kk = 0; kk < 16; kk++) wreg[kk] = *(const bf16x8*)(wb + kk * 512);
    }

    // --- elementwise mapping: thread -> (b, j0, j1) ---
    const int b  = tid >> 3;            // 0..31
    const int jp = tid & 7;
    const int j0 = w * 16 + jp * 2;     // global h column (even)
    f32x2 bsv[4];
#pragma unroll
    for (int g = 0; g < 4; g++) bsv[g] = *(const f32x2*)(bias + g * 512 + j0);
    float cc0 = 0.f, cc1 = 0.f;

    // A-frag lane offsets into h_lds (bf16 elements)
    const int arow = lane & 15;
    const int kq8  = (lane >> 4) * 8;

    // xp prefetch: u32 per gate = 2 contiguous bf16 at (b, j0)
    u32 xc[4], xn[4];
#pragma unroll
    for (int g = 0; g < 4; g++)
        xc[g] = *(const u32*)(xp + (size_t)b * 2048 + g * 512 + j0);

    for (int t = 0; t < 1024; t++) {
        // prefetch xp[t+1] (independent of h)
        {
            int tn = (t < 1023) ? t + 1 : 1023;
#pragma unroll
            for (int g = 0; g < 4; g++)
                xn[g] = *(const u32*)(xp + (size_t)(tn * 32 + b) * 2048 + g * 512 + j0);
        }

        // --- stage h[t]: 16 batched atomic u64 loads -> LDS mirror ---
        {
            const u64* hg = (const u64*)(hbuf + (size_t)(t & 1) * 16384);
            u64 hv[16];
#pragma unroll
            for (int i = 0; i < 16; i++)
                hv[i] = __hip_atomic_load(hg + i * 256 + tid, __ATOMIC_RELAXED, SCOPE_AGENT);
#pragma unroll
            for (int i = 0; i < 16; i++) {
                int f  = (i * 256 + tid) * 4;   // bf16 flat idx in [0, 16384)
                int br = f >> 9, col = f & 511;
                *(u64*)(h_lds + br * 516 + col) = hv[i];
            }
        }
        __syncthreads();

        // --- MFMA: gates[b][gatecol] = h @ Wslice^T ---
        f32x4 acc0 = (f32x4){0.f, 0.f, 0.f, 0.f};
        f32x4 acc1 = (f32x4){0.f, 0.f, 0.f, 0.f};
#pragma unroll
        for (int kk = 0; kk < 16; kk++) {
            const __bf16* p0 = h_lds + arow * 516 + kq8 + kk * 32;
            const __bf16* p1 = p0 + 16 * 516;
            bf16x8 a0 = frag_from(*(const u64*)p0, *(const u64*)(p0 + 4));
            bf16x8 a1 = frag_from(*(const u64*)p1, *(const u64*)(p1 + 4));
            acc0 = MFMA16(a0, wreg[kk], acc0);
            acc1 = MFMA16(a1, wreg[kk], acc1);
        }
        // C frag: row=(lane>>4)*4+r -> batch, col=lane&15 -> gate col
        {
            int col   = wv * 16 + (lane & 15);
            int rbase = (lane >> 4) * 4;
#pragma unroll
            for (int r = 0; r < 4; r++) {
                g_lds[(rbase + r) * 68 + col]      = acc0[r];
                g_lds[(16 + rbase + r) * 68 + col] = acc1[r];
            }
        }
        __syncthreads();

        // --- gate math: thread owns (b, j0, j1) ---
        float hf0, hf1;
        {
            union { u32 u; __bf16 v[2]; } xi, xf, xg, xo;
            xi.u = xc[0]; xf.u = xc[1]; xg.u = xc[2]; xo.u = xc[3];
            const float* gl = g_lds + b * 68 + jp * 2;
            f32x2 gi = *(const f32x2*)(gl);
            f32x2 gf = *(const f32x2*)(gl + 16);
            f32x2 gg = *(const f32x2*)(gl + 32);
            f32x2 go = *(const f32x2*)(gl + 48);

            float i0 = fsigm(gi[0] + (float)xi.v[0] + bsv[0][0]);
            float f0 = fsigm(gf[0] + (float)xf.v[0] + bsv[1][0]);
            float g0 = ftanh(gg[0] + (float)xg.v[0] + bsv[2][0]);
            float o0 = fsigm(go[0] + (float)xo.v[0] + bsv[3][0]);
            cc0 = f0 * cc0 + i0 * g0;
            hf0 = o0 * ftanh(cc0);

            float i1 = fsigm(gi[1] + (float)xi.v[1] + bsv[0][1]);
            float f1 = fsigm(gf[1] + (float)xf.v[1] + bsv[1][1]);
            float g1 = ftanh(gg[1] + (float)xg.v[1] + bsv[2][1]);
            float o1 = fsigm(go[1] + (float)xo.v[1] + bsv[3][1]);
            cc1 = f1 * cc1 + i1 * g1;
            hf1 = o1 * ftanh(cc1);
        }
        union { __bf16 v[2]; u32 u; } hu;
        hu.v[0] = (__bf16)hf0; hu.v[1] = (__bf16)hf1;

        // h store (atomic, write-through to coherence point)
        __bf16* hnx = hbuf + (size_t)((t + 1) & 1) * 16384;
        __hip_atomic_store((u32*)(hnx + (size_t)b * 512 + j0), hu.u,
                           __ATOMIC_RELAXED, SCOPE_AGENT);

        if (t < 1023) {
            asm volatile("s_waitcnt vmcnt(0)" ::: "memory");  // h stores drained
            __syncthreads();                                   // whole wg done
            if (tid == 0)
                __hip_atomic_store(&flags[t * 32 + w], 1, __ATOMIC_RELAXED, SCOPE_AGENT);
            // overlap non-critical stores with flag propagation
            if (layer == 0)
                *(u32*)(hs0_bf + ((size_t)t * 32 + b) * 512 + j0) = hu.u;
            else {
                f32x2 hf2 = (f32x2){hf0, hf1};
                *(f32x2*)(out_f32 + (size_t)b * 524288 + (size_t)t * 512 + j0) = hf2;
            }
            if (tid < 32) {
                while (__hip_atomic_load(&flags[t * 32 + tid], __ATOMIC_RELAXED,
                                         SCOPE_AGENT) == 0) {}
            }
            asm volatile("" ::: "memory");
            __syncthreads();
        } else {
            if (layer == 0)
                *(u32*)(hs0_bf + ((size_t)t * 32 + b) * 512 + j0) = hu.u;
            else {
                f32x2 hf2 = (f32x2){hf0, hf1};
                *(f32x2*)(out_f32 + (size_t)b * 524288 + (size_t)t * 512 + j0) = hf2;
            }
            *(f32x2*)(hn_out + (size_t)b * 512 + j0) = (f32x2){hf0, hf1};
            *(f32x2*)(cn_out + (size_t)b * 512 + j0) = (f32x2){cc0, cc1};
        }
#pragma unroll
        for (int g = 0; g < 4; g++) xc[g] = xn[g];
    }
}

// ---------------------------------------------------------------------------
extern "C" void kernel_launch(void* const* d_in, const int* in_sizes, int n_in,
                              void* d_out, int out_size, void* d_ws, size_t ws_size,
                              hipStream_t stream) {
    (void)in_sizes; (void)n_in; (void)out_size; (void)ws_size;
    const float* x    = (const float*)d_in[0];  // [32][1024][256] fp32
    const float* Wih0 = (const float*)d_in[1];  // [2048][256] fp32
    const float* b0   = (const float*)d_in[2];  // [2048] fp32
    const float* Whh0 = (const float*)d_in[3];  // [2048][512] fp32
    const float* Wih1 = (const float*)d_in[4];  // [2048][512] fp32
    const float* b1   = (const float*)d_in[5];  // [2048] fp32
    const float* Whh1 = (const float*)d_in[6];  // [2048][512] fp32
    float* dout = (float*)d_out;  // fp32: out(16777216) | h_n(2*16384) | c_n(2*16384)

    char* wsb = (char*)d_ws;
    int*    flags = (int*)wsb;                                   // 256 KB (2 layers)
    __bf16* hbuf0 = (__bf16*)(wsb + (256 << 10));                // 64 KB
    __bf16* hbuf1 = (__bf16*)(wsb + (320 << 10));                // 64 KB
    __bf16* WB0   = (__bf16*)(wsb + (384 << 10));                // 2 MB
    __bf16* WB1   = (__bf16*)(wsb + (384 << 10) + (2 << 20));    // 2 MB
    __bf16* hs0   = (__bf16*)(wsb + (384 << 10) + (4 << 20));    // 32 MB
    __bf16* xpb   = (__bf16*)(wsb + (384 << 10) + (36 << 20));   // 128 MB (xp0/xp1 shared)

    // zero flags + both h double-buffers (contiguous 384 KB)
    (void)hipMemsetAsync(wsb, 0, 384 << 10, stream);

    pack_w<<<dim3(1024), dim3(256), 0, stream>>>(Whh0, Whh1, WB0, WB1);

    // layer 0: xp0 = x @ Wih0^T  (K=256, fp32 A, permuted rows)
    gemm_xp<<<dim3(4096), dim3(256), 0, stream>>>((const void*)x, Wih0, xpb, 256, 1);
    lstm_rec<<<dim3(32), dim3(256), 0, stream>>>(
        xpb, WB0, b0, hbuf0, hs0, (float*)nullptr,
        dout + 16777216, dout + 16777216 + 32768, flags, 0);

    // layer 1: xp1 = hs0 @ Wih1^T  (K=512, bf16 A row-major)
    gemm_xp<<<dim3(4096), dim3(256), 0, stream>>>((const void*)hs0, Wih1, xpb, 512, 0);
    lstm_rec<<<dim3(32), dim3(256), 0, stream>>>(
        xpb, WB1, b1, hbuf1, (__bf16*)nullptr, dout,
        dout + 16777216 + 16384, dout + 16777216 + 32768 + 16384, flags + 32768, 1);
}

// Round 7
// 5122.392 us; speedup vs baseline: 4.4206x; 1.5195x over previous
//
#include <hip/hip_runtime.h>

// ---------------------------------------------------------------------------
// 2-layer LSTM, T=1024, B=32, D=256, H=512. Inputs fp32, OUTPUT fp32.
//   pack_w3: fp32 {W_hh0, W_hh1, W_ih1} -> bf16 MFMA B-fragment order.
//   gemm_xp: xp0 = x @ W_ih0^T (bf16 MFMA), [t*32+b][2048] bf16.
//   lstm_fused: persistent 64-wg kernel. wgs 0..31 = layer0, 32..63 = layer1
//     (lagging 1 step, consuming hs0[t] directly; computes hs0@W_ih1^T with
//     register-resident W_ih1 instead of a precomputed xp1). Fence-free
//     relaxed agent-atomic exchange (proven R5/R6); batched atomic loads ->
//     LDS mirrors; flags spread to private cache lines (R6: all 32 flags in
//     one MALL line -> serialized stores/polls).
// ---------------------------------------------------------------------------

typedef __bf16 bf16x8 __attribute__((ext_vector_type(8)));
typedef float  f32x4  __attribute__((ext_vector_type(4)));
typedef float  f32x2  __attribute__((ext_vector_type(2)));
typedef unsigned long long u64;
typedef unsigned int u32;

#define MFMA16(a, b, c) __builtin_amdgcn_mfma_f32_16x16x32_bf16((a), (b), (c), 0, 0, 0)
#define SCOPE_AGENT __HIP_MEMORY_SCOPE_AGENT

__device__ __forceinline__ float fsigm(float x) { return 1.0f / (1.0f + __expf(-x)); }
__device__ __forceinline__ float ftanh(float x) {
    x = fminf(15.0f, fmaxf(-15.0f, x));
    float e = __expf(2.0f * x);
    return (e - 1.0f) / (e + 1.0f);
}

__device__ __forceinline__ bf16x8 frag_from(u64 lo, u64 hi) {
    union { u64 u[2]; bf16x8 v; } x;
    x.u[0] = lo; x.u[1] = hi;
    return x.v;
}

// ---------------------------------------------------------------------------
// Pack [2048][512] fp32 -> per-(wg,wave,ktile) bf16 B-fragment order:
//   WB[((w*4+v)*16+kk)*512 + lane*8 + e] = bf16(W[grow][k0+e])
//   n = v*16+(lane&15); grow = (n>>4)*512 + w*16 + (n&15); k0 = kk*32+(lane>>4)*8
// Three matrices: W_hh0, W_hh1, W_ih1.
// ---------------------------------------------------------------------------
__global__ void pack_w3(const float* __restrict__ W0, const float* __restrict__ W1,
                        const float* __restrict__ W2, __bf16* __restrict__ O0,
                        __bf16* __restrict__ O1, __bf16* __restrict__ O2) {
    int gtid = blockIdx.x * 256 + threadIdx.x;          // 0 .. 393215
    int sel  = gtid >> 17;                              // 0,1,2
    const float* W = (sel == 0) ? W0 : (sel == 1) ? W1 : W2;
    __bf16* WB     = (sel == 0) ? O0 : (sel == 1) ? O1 : O2;
    int tid  = gtid & 131071;
    int lane = tid & 63;
    int kk   = (tid >> 6) & 15;
    int v    = (tid >> 10) & 3;
    int w    = tid >> 12;                               // 0..31
    int n    = v * 16 + (lane & 15);
    int grow = (n >> 4) * 512 + w * 16 + (n & 15);
    int k0   = kk * 32 + (lane >> 4) * 8;
    const float* src = W + (size_t)grow * 512 + k0;
    bf16x8 val;
#pragma unroll
    for (int e = 0; e < 8; e++) val[e] = (__bf16)src[e];
    *(bf16x8*)(WB + (size_t)tid * 8) = val;
}

// ---------------------------------------------------------------------------
// xp0[r][n] = sum_k x_perm(r)[k] * W[n][k], r = t*32+b, x is [B,T,D] fp32.
// ---------------------------------------------------------------------------
__global__ __launch_bounds__(256, 2) void gemm_xp(const float* __restrict__ A,
                                                  const float* __restrict__ W,
                                                  __bf16* __restrict__ out, int K) {
    const int tid = threadIdx.x, lane = tid & 63, wv = tid >> 6;
    const int bm = blockIdx.x >> 4, bn = blockIdx.x & 15;
    const int m_base = bm * 128 + (wv & 1) * 64;
    const int n_base = bn * 128 + (wv >> 1) * 64;
    const int kq = (lane >> 4) * 8;
    const int rl = lane & 15;

    f32x4 acc[4][4];
#pragma unroll
    for (int i = 0; i < 4; i++)
#pragma unroll
        for (int j = 0; j < 4; j++) acc[i][j] = (f32x4){0.f, 0.f, 0.f, 0.f};

    const int nk = K >> 5;
    for (int kk = 0; kk < nk; kk++) {
        int k0 = kk * 32 + kq;
        bf16x8 af[4], bfr[4];
#pragma unroll
        for (int mt = 0; mt < 4; mt++) {
            int row = m_base + mt * 16 + rl;
            const float* ap = A + (size_t)((row & 31) * 1024 + (row >> 5)) * K + k0;
#pragma unroll
            for (int e = 0; e < 8; e++) af[mt][e] = (__bf16)ap[e];
        }
#pragma unroll
        for (int nt = 0; nt < 4; nt++) {
            int n = n_base + nt * 16 + rl;
            const float* wp = W + (size_t)n * K + k0;
#pragma unroll
            for (int e = 0; e < 8; e++) bfr[nt][e] = (__bf16)wp[e];
        }
#pragma unroll
        for (int mt = 0; mt < 4; mt++)
#pragma unroll
            for (int nt = 0; nt < 4; nt++)
                acc[mt][nt] = MFMA16(af[mt], bfr[nt], acc[mt][nt]);
    }

    const int rq = (lane >> 4) * 4;
#pragma unroll
    for (int mt = 0; mt < 4; mt++)
#pragma unroll
        for (int nt = 0; nt < 4; nt++)
#pragma unroll
            for (int r = 0; r < 4; r++) {
                int row = m_base + mt * 16 + rq + r;
                int col = n_base + nt * 16 + rl;
                out[(size_t)row * 2048 + col] = (__bf16)acc[mt][nt][r];
            }
}

// ---------------------------------------------------------------------------
// Fused pipelined recurrence: 64 wgs x 256. wg<32: layer0 (w=wg); wg>=32:
// layer1 (w=wg-32), lagging layer0 by one step. Flags: private line per wg:
// flagsL[w*1024 + t]. Layer0 step t: hbuf0 exchange among layer0 wgs, writes
// hs0[t] (atomic) pre-flag. Layer1 step t: waits flags0[*,t], stages hs0[t]
// + hbuf1 state, 64 MFMAs (Whh1 + Wih1), writes out row t.
// ---------------------------------------------------------------------------
__global__ __launch_bounds__(256, 1) void lstm_fused(
    const __bf16* __restrict__ xp0,   // [32768][2048] bf16, row = t*32+b
    const __bf16* __restrict__ WB0,   // W_hh0 packed
    const __bf16* __restrict__ WB1,   // W_hh1 packed
    const __bf16* __restrict__ WBi1,  // W_ih1 packed
    const float* __restrict__ bias0,
    const float* __restrict__ bias1,
    __bf16* __restrict__ hbuf0,       // [2][32][512] zeroed
    __bf16* __restrict__ hbuf1,       // [2][32][512] zeroed
    __bf16* __restrict__ hs0_bf,      // [1024*32][512]
    float* __restrict__ out_f32,      // [32][1024][512]
    float* __restrict__ hn_out,       // [2][32][512]
    float* __restrict__ cn_out,       // [2][32][512]
    int* __restrict__ flags0,         // [32][1024] zeroed
    int* __restrict__ flags1) {       // [32][1024] zeroed
    const int tid   = threadIdx.x;
    const int wg    = blockIdx.x;   // 0..63
    const int layer = wg >> 5;
    const int w     = wg & 31;
    const int lane  = tid & 63;
    const int wv    = tid >> 6;

    __shared__ __bf16 h_lds[32 * 516];  // h-state mirror (stride 516)
    __shared__ __bf16 s_lds[32 * 516];  // hs0[t] mirror (layer1)
    __shared__ float  g_lds[32 * 68];   // gates [32 b][64 cols], +4 pad

    // --- weights resident in registers ---
    bf16x8 wregA[16], wregB[16];
    {
        const size_t wo = (size_t)(w * 4 + wv) * 16 * 512 + lane * 8;
        const __bf16* wa = (layer ? WB1 : WB0) + wo;
#pragma unroll
        for (int kk = 0; kk < 16; kk++) wregA[kk] = *(const bf16x8*)(wa + kk * 512);
        if (layer) {
            const __bf16* wb = WBi1 + wo;
#pragma unroll
            for (int kk = 0; kk < 16; kk++) wregB[kk] = *(const bf16x8*)(wb + kk * 512);
        }
    }

    const float* bias = layer ? bias1 : bias0;
    __bf16* hbuf  = layer ? hbuf1 : hbuf0;
    int* flagsMy  = layer ? flags1 : flags0;

    // --- elementwise mapping: thread -> (b, j0, j0+1) ---
    const int b  = tid >> 3;
    const int jp = tid & 7;
    const int j0 = w * 16 + jp * 2;
    f32x2 bsv[4];
#pragma unroll
    for (int g = 0; g < 4; g++) bsv[g] = *(const f32x2*)(bias + g * 512 + j0);
    float cc0 = 0.f, cc1 = 0.f;

    const int arow = lane & 15;
    const int kq8  = (lane >> 4) * 8;

    // xp prefetch (layer0 only; layer1 adds zero)
    u32 xc[4] = {0, 0, 0, 0}, xn[4] = {0, 0, 0, 0};
    if (!layer) {
#pragma unroll
        for (int g = 0; g < 4; g++)
            xc[g] = *(const u32*)(xp0 + (size_t)b * 2048 + g * 512 + j0);
    }

    for (int t = 0; t < 1024; t++) {
        if (!layer) {
            int tn = (t < 1023) ? t + 1 : 1023;
#pragma unroll
            for (int g = 0; g < 4; g++)
                xn[g] = *(const u32*)(xp0 + (size_t)(tn * 32 + b) * 2048 + g * 512 + j0);
        } else {
            // wait for layer0 to finish step t (hs0[t] committed)
            if (tid < 32) {
                while (__hip_atomic_load(&flags0[tid * 1024 + t], __ATOMIC_RELAXED,
                                         SCOPE_AGENT) == 0) {}
            }
            asm volatile("" ::: "memory");
            __syncthreads();
        }

        // --- stage h state (and hs0[t] for layer1): batched atomic loads ---
        {
            const u64* hg = (const u64*)(hbuf + (size_t)(t & 1) * 16384);
            u64 hv[16];
#pragma unroll
            for (int i = 0; i < 16; i++)
                hv[i] = __hip_atomic_load(hg + i * 256 + tid, __ATOMIC_RELAXED, SCOPE_AGENT);
            if (layer) {
                const u64* sg = (const u64*)(hs0_bf + (size_t)t * 16384);
                u64 sv[16];
#pragma unroll
                for (int i = 0; i < 16; i++)
                    sv[i] = __hip_atomic_load(sg + i * 256 + tid, __ATOMIC_RELAXED, SCOPE_AGENT);
#pragma unroll
                for (int i = 0; i < 16; i++) {
                    int f  = (i * 256 + tid) * 4;
                    int br = f >> 9, col = f & 511;
                    *(u64*)(s_lds + br * 516 + col) = sv[i];
                }
            }
#pragma unroll
            for (int i = 0; i < 16; i++) {
                int f  = (i * 256 + tid) * 4;
                int br = f >> 9, col = f & 511;
                *(u64*)(h_lds + br * 516 + col) = hv[i];
            }
        }
        __syncthreads();

        // --- MFMA: gates[b][gatecol] = h @ Whh^T (+ hs0 @ Wih1^T) ---
        f32x4 acc0 = (f32x4){0.f, 0.f, 0.f, 0.f};
        f32x4 acc1 = (f32x4){0.f, 0.f, 0.f, 0.f};
#pragma unroll
        for (int kk = 0; kk < 16; kk++) {
            const __bf16* p0 = h_lds + arow * 516 + kq8 + kk * 32;
            const __bf16* p1 = p0 + 16 * 516;
            bf16x8 a0 = frag_from(*(const u64*)p0, *(const u64*)(p0 + 4));
            bf16x8 a1 = frag_from(*(const u64*)p1, *(const u64*)(p1 + 4));
            acc0 = MFMA16(a0, wregA[kk], acc0);
            acc1 = MFMA16(a1, wregA[kk], acc1);
        }
        if (layer) {
#pragma unroll
            for (int kk = 0; kk < 16; kk++) {
                const __bf16* p0 = s_lds + arow * 516 + kq8 + kk * 32;
                const __bf16* p1 = p0 + 16 * 516;
                bf16x8 a0 = frag_from(*(const u64*)p0, *(const u64*)(p0 + 4));
                bf16x8 a1 = frag_from(*(const u64*)p1, *(const u64*)(p1 + 4));
                acc0 = MFMA16(a0, wregB[kk], acc0);
                acc1 = MFMA16(a1, wregB[kk], acc1);
            }
        }
        {
            int col   = wv * 16 + (lane & 15);
            int rbase = (lane >> 4) * 4;
#pragma unroll
            for (int r = 0; r < 4; r++) {
                g_lds[(rbase + r) * 68 + col]      = acc0[r];
                g_lds[(16 + rbase + r) * 68 + col] = acc1[r];
            }
        }
        __syncthreads();

        // --- gate math: thread owns (b, j0, j0+1) ---
        float hf0, hf1;
        {
            union { u32 u; __bf16 v[2]; } xi, xf, xg, xo;
            xi.u = xc[0]; xf.u = xc[1]; xg.u = xc[2]; xo.u = xc[3];
            const float* gl = g_lds + b * 68 + jp * 2;
            f32x2 gi = *(const f32x2*)(gl);
            f32x2 gf = *(const f32x2*)(gl + 16);
            f32x2 gg = *(const f32x2*)(gl + 32);
            f32x2 go = *(const f32x2*)(gl + 48);

            float i0 = fsigm(gi[0] + (float)xi.v[0] + bsv[0][0]);
            float f0 = fsigm(gf[0] + (float)xf.v[0] + bsv[1][0]);
            float g0 = ftanh(gg[0] + (float)xg.v[0] + bsv[2][0]);
            float o0 = fsigm(go[0] + (float)xo.v[0] + bsv[3][0]);
            cc0 = f0 * cc0 + i0 * g0;
            hf0 = o0 * ftanh(cc0);

            float i1 = fsigm(gi[1] + (float)xi.v[1] + bsv[0][1]);
            float f1 = fsigm(gf[1] + (float)xf.v[1] + bsv[1][1]);
            float g1 = ftanh(gg[1] + (float)xg.v[1] + bsv[2][1]);
            float o1 = fsigm(go[1] + (float)xo.v[1] + bsv[3][1]);
            cc1 = f1 * cc1 + i1 * g1;
            hf1 = o1 * ftanh(cc1);
        }
        union { __bf16 v[2]; u32 u; } hu;
        hu.v[0] = (__bf16)hf0; hu.v[1] = (__bf16)hf1;

        // h store + (layer0) hs0[t] store — both pre-flag, atomic
        __bf16* hnx = hbuf + (size_t)((t + 1) & 1) * 16384;
        __hip_atomic_store((u32*)(hnx + (size_t)b * 512 + j0), hu.u,
                           __ATOMIC_RELAXED, SCOPE_AGENT);
        if (!layer)
            __hip_atomic_store((u32*)(hs0_bf + ((size_t)t * 32 + b) * 512 + j0), hu.u,
                               __ATOMIC_RELAXED, SCOPE_AGENT);

        // --- flag set (private line per wg) + poll ---
        asm volatile("s_waitcnt vmcnt(0)" ::: "memory");
        __syncthreads();
        if (tid == 0 && (t < 1023 || !layer))
            __hip_atomic_store(&flagsMy[w * 1024 + t], 1, __ATOMIC_RELAXED, SCOPE_AGENT);

        if (t < 1023) {
            // overlap non-critical store with flag propagation
            if (layer) {
                f32x2 hf2 = (f32x2){hf0, hf1};
                *(f32x2*)(out_f32 + (size_t)b * 524288 + (size_t)t * 512 + j0) = hf2;
            }
            if (tid < 32) {
                while (__hip_atomic_load(&flagsMy[tid * 1024 + t], __ATOMIC_RELAXED,
                                         SCOPE_AGENT) == 0) {}
            }
            asm volatile("" ::: "memory");
            __syncthreads();
        } else {
            if (layer) {
                f32x2 hf2 = (f32x2){hf0, hf1};
                *(f32x2*)(out_f32 + (size_t)b * 524288 + (size_t)t * 512 + j0) = hf2;
            }
            float* hn = hn_out + (size_t)layer * 16384;
            float* cn = cn_out + (size_t)layer * 16384;
            *(f32x2*)(hn + (size_t)b * 512 + j0) = (f32x2){hf0, hf1};
            *(f32x2*)(cn + (size_t)b * 512 + j0) = (f32x2){cc0, cc1};
        }
#pragma unroll
        for (int g = 0; g < 4; g++) xc[g] = xn[g];
    }
}

// ---------------------------------------------------------------------------
extern "C" void kernel_launch(void* const* d_in, const int* in_sizes, int n_in,
                              void* d_out, int out_size, void* d_ws, size_t ws_size,
                              hipStream_t stream) {
    (void)in_sizes; (void)n_in; (void)out_size; (void)ws_size;
    const float* x    = (const float*)d_in[0];  // [32][1024][256] fp32
    const float* Wih0 = (const float*)d_in[1];  // [2048][256] fp32
    const float* b0   = (const float*)d_in[2];  // [2048] fp32
    const float* Whh0 = (const float*)d_in[3];  // [2048][512] fp32
    const float* Wih1 = (const float*)d_in[4];  // [2048][512] fp32
    const float* b1   = (const float*)d_in[5];  // [2048] fp32
    const float* Whh1 = (const float*)d_in[6];  // [2048][512] fp32
    float* dout = (float*)d_out;  // fp32: out(16777216) | h_n(2*16384) | c_n(2*16384)

    char* wsb = (char*)d_ws;
    int*    flags0 = (int*)wsb;                                  // 128 KB
    int*    flags1 = (int*)(wsb + (128 << 10));                  // 128 KB
    __bf16* hbuf0  = (__bf16*)(wsb + (256 << 10));               // 64 KB
    __bf16* hbuf1  = (__bf16*)(wsb + (320 << 10));               // 64 KB
    __bf16* WB0    = (__bf16*)(wsb + (384 << 10));               // 2 MB
    __bf16* WB1    = (__bf16*)(wsb + (384 << 10) + (2 << 20));   // 2 MB
    __bf16* WBi1   = (__bf16*)(wsb + (384 << 10) + (4 << 20));   // 2 MB
    __bf16* hs0    = (__bf16*)(wsb + (384 << 10) + (6 << 20));   // 32 MB
    __bf16* xpb    = (__bf16*)(wsb + (384 << 10) + (38 << 20));  // 128 MB

    // zero flags + both h double-buffers (contiguous 384 KB)
    (void)hipMemsetAsync(wsb, 0, 384 << 10, stream);

    pack_w3<<<dim3(1536), dim3(256), 0, stream>>>(Whh0, Whh1, Wih1, WB0, WB1, WBi1);

    // xp0 = x @ Wih0^T  (K=256, fp32 A, permuted rows)
    gemm_xp<<<dim3(4096), dim3(256), 0, stream>>>(x, Wih0, xpb, 256);

    lstm_fused<<<dim3(64), dim3(256), 0, stream>>>(
        xpb, WB0, WB1, WBi1, b0, b1, hbuf0, hbuf1, hs0,
        dout, dout + 16777216, dout + 16777216 + 32768, flags0, flags1);
}